// Round 4
// baseline (1030.971 us; speedup 1.0000x reference)
//
#include <hip/hip_runtime.h>
#include <math.h>

// Problem constants
#define B_ 32
#define D_ 512
#define N_ 1024            // H*W
#define T_ 32768           // B_*N_
#define SCALE 0.04419417382415922f  // 512^-0.5

// GEMM tile config
#define BM 64
#define BN 64
#define BK 16
#define LDA 68             // BM + 4 pad (keeps 16B alignment: 68*4=272=17*16)
#define LDB 68

__device__ inline float waveRedSum(float v) {
#pragma unroll
    for (int off = 32; off > 0; off >>= 1) v += __shfl_xor(v, off, 64);
    return v;
}

// MODE 0: A = x in [B][C][N] layout; out = A@W^T + bias, row-major [T][D]
// MODE 1: A = key row-major [T][D], scaled per-column by g[batch][c];
//         out = A'@W^T + bias + q (query add); out may alias q (tile-exclusive)
// MODE 2: A = tmp row-major [T][D]; out = A@W^T + bias, stored TRANSPOSED
//         to [B][D][N] (final output layout)
template <int MODE>
__global__ __launch_bounds__(256) void gemm_k(const float* __restrict__ A,
                                              const float* __restrict__ W,
                                              const float* __restrict__ bias,
                                              const float* __restrict__ g,
                                              const float* q,
                                              float* out) {
    __shared__ float As[BK][LDA];
    __shared__ float Bs[BK][LDB];
    const int tid = threadIdx.x;
    const int bn = blockIdx.x;   // col tile (fastest -> A-panel L3 reuse)
    const int bt = blockIdx.y;   // row tile
    const int t0 = bt * BM;
    const int e0 = bn * BN;
    const int batch = t0 >> 10;  // BM=64 divides 1024: tiles never straddle batches
    const int n0 = t0 & 1023;

    const int tx = tid & 15;
    const int ty = tid >> 4;
    // MODE2 maps rows to tx so the transposed store is coalesced (float4 along n)
    const int mB = (MODE == 2) ? (tx * 4) : (ty * 4);
    const int nB = (MODE == 2) ? (ty * 4) : (tx * 4);

    float acc[4][4];
#pragma unroll
    for (int i = 0; i < 4; ++i)
#pragma unroll
        for (int j = 0; j < 4; ++j) acc[i][j] = 0.f;

    // staging index helpers
    const int sm = tid & 63;           // MODE0: m within tile
    const int sk0 = (tid >> 6) * 4;    // MODE0: k base (4 strided loads)
    const int am = tid >> 2;           // MODE1/2: row within tile
    const int ak = (tid & 3) * 4;      // MODE1/2: k base (one float4)
    const int wd = tid >> 2;           // B stage: weight row within tile
    const int wk = (tid & 3) * 4;

    for (int c0 = 0; c0 < D_; c0 += BK) {
        // ---- stage A tile -> As[k][m]
        if (MODE == 0) {
            const float* src = A + ((size_t)(batch * D_ + c0 + sk0)) * N_ + n0 + sm;
#pragma unroll
            for (int j = 0; j < 4; ++j) As[sk0 + j][sm] = src[(size_t)j * N_];
        } else {
            float4 v = *(const float4*)(A + (size_t)(t0 + am) * D_ + c0 + ak);
            if (MODE == 1) {
                const float4 gv = *(const float4*)(g + batch * D_ + c0 + ak);
                v.x *= gv.x; v.y *= gv.y; v.z *= gv.z; v.w *= gv.w;
            }
            As[ak + 0][am] = v.x;
            As[ak + 1][am] = v.y;
            As[ak + 2][am] = v.z;
            As[ak + 3][am] = v.w;
        }
        // ---- stage B tile (weights, row-major [d][c]) -> Bs[k][d]
        {
            const float4 v = *(const float4*)(W + (size_t)(e0 + wd) * D_ + c0 + wk);
            Bs[wk + 0][wd] = v.x;
            Bs[wk + 1][wd] = v.y;
            Bs[wk + 2][wd] = v.z;
            Bs[wk + 3][wd] = v.w;
        }
        __syncthreads();
#pragma unroll
        for (int k = 0; k < BK; ++k) {
            const float4 a = *(const float4*)&As[k][mB];
            const float4 b = *(const float4*)&Bs[k][nB];
            acc[0][0] += a.x * b.x; acc[0][1] += a.x * b.y;
            acc[0][2] += a.x * b.z; acc[0][3] += a.x * b.w;
            acc[1][0] += a.y * b.x; acc[1][1] += a.y * b.y;
            acc[1][2] += a.y * b.z; acc[1][3] += a.y * b.w;
            acc[2][0] += a.z * b.x; acc[2][1] += a.z * b.y;
            acc[2][2] += a.z * b.z; acc[2][3] += a.z * b.w;
            acc[3][0] += a.w * b.x; acc[3][1] += a.w * b.y;
            acc[3][2] += a.w * b.z; acc[3][3] += a.w * b.w;
        }
        __syncthreads();
    }

    // ---- epilogue
    if (MODE == 2) {
        // transposed store: out[batch][e][n], float4 along n
#pragma unroll
        for (int j = 0; j < 4; ++j) {
            const int e = e0 + nB + j;
            const float bb = bias[e];
            float4 r;
            r.x = acc[0][j] + bb;
            r.y = acc[1][j] + bb;
            r.z = acc[2][j] + bb;
            r.w = acc[3][j] + bb;
            *(float4*)(out + (size_t)(batch * D_ + e) * N_ + n0 + mB) = r;
        }
    } else {
        const float4 bv = *(const float4*)(bias + e0 + nB);
#pragma unroll
        for (int i = 0; i < 4; ++i) {
            const int t = t0 + mB + i;
            float4 r;
            r.x = acc[i][0] + bv.x;
            r.y = acc[i][1] + bv.y;
            r.z = acc[i][2] + bv.z;
            r.w = acc[i][3] + bv.w;
            if (MODE == 1) {
                const float4 qv = *(const float4*)(q + (size_t)t * D_ + e0 + nB);
                r.x += qv.x; r.y += qv.y; r.z += qv.z; r.w += qv.w;
            }
            *(float4*)(out + (size_t)t * D_ + e0 + nB) = r;
        }
    }
}

// Row-wise l2 normalize (in place) for Q (y==0) and K (y==1).
// For Q also computes qw[row] = dot(q_norm, w_g).
// One wave per row, 4 rows per block.
__global__ __launch_bounds__(256) void rownorm_k(float* Q, float* K,
                                                 const float* __restrict__ wg,
                                                 float* __restrict__ qw) {
    const int lane = threadIdx.x & 63;
    const int wv = threadIdx.x >> 6;
    const int row = blockIdx.x * 4 + wv;
    const int isK = blockIdx.y;
    float* base = (isK ? K : Q) + (size_t)row * D_;
    float4 v0 = *(float4*)(base + lane * 8);
    float4 v1 = *(float4*)(base + lane * 8 + 4);
    float ss = v0.x * v0.x + v0.y * v0.y + v0.z * v0.z + v0.w * v0.w +
               v1.x * v1.x + v1.y * v1.y + v1.z * v1.z + v1.w * v1.w;
    ss = waveRedSum(ss);
    const float sc = 1.f / fmaxf(sqrtf(ss), 1e-12f);
    v0.x *= sc; v0.y *= sc; v0.z *= sc; v0.w *= sc;
    v1.x *= sc; v1.y *= sc; v1.z *= sc; v1.w *= sc;
    *(float4*)(base + lane * 8) = v0;
    *(float4*)(base + lane * 8 + 4) = v1;
    if (!isK) {
        const float4 w0 = *(const float4*)(wg + lane * 8);
        const float4 w1 = *(const float4*)(wg + lane * 8 + 4);
        float d = v0.x * w0.x + v0.y * w0.y + v0.z * w0.z + v0.w * w0.w +
                  v1.x * w1.x + v1.y * w1.y + v1.z * w1.z + v1.w * w1.w;
        d = waveRedSum(d);
        if (lane == 0) qw[row] = d;
    }
}

// Per batch: a = l2norm(qw*scale over n). Fold into qw in place:
// qw[b,n] *= scale / max(scale*sqrt(sum qw^2), eps)
__global__ __launch_bounds__(256) void qwscale_k(float* __restrict__ qw) {
    __shared__ float red[4];
    const int b = blockIdx.x;
    float* p = qw + (size_t)b * N_ + threadIdx.x * 4;
    float4 v = *(float4*)p;
    float ss = v.x * v.x + v.y * v.y + v.z * v.z + v.w * v.w;
    ss = waveRedSum(ss);
    if ((threadIdx.x & 63) == 0) red[threadIdx.x >> 6] = ss;
    __syncthreads();
    const float S = red[0] + red[1] + red[2] + red[3];
    const float denom = fmaxf(SCALE * sqrtf(S), 1e-12f);
    const float f = SCALE / denom;
    v.x *= f; v.y *= f; v.z *= f; v.w *= f;
    *(float4*)p = v;
}

// g[b,d] = sum_n qw[b,n] * Q[b,n,d]  (qw already contains the 'a' weights)
// Grid (8 n-chunks, B). Coalesced along d; atomicAdd partials.
__global__ __launch_bounds__(512) void gctx_k(const float* __restrict__ qw,
                                              const float* __restrict__ Q,
                                              float* __restrict__ g) {
    const int b = blockIdx.y;
    const int n0 = blockIdx.x * 128;
    const int d = threadIdx.x;
    const float* qp = Q + ((size_t)b * N_ + n0) * D_ + d;
    const float* wp = qw + (size_t)b * N_ + n0;
    float acc = 0.f;
    for (int n = 0; n < 128; ++n) acc += wp[n] * qp[(size_t)n * D_];
    atomicAdd(g + b * D_ + d, acc);
}

extern "C" void kernel_launch(void* const* d_in, const int* in_sizes, int n_in,
                              void* d_out, int out_size, void* d_ws, size_t ws_size,
                              hipStream_t stream) {
    const float* x  = (const float*)d_in[0];
    const float* Wq = (const float*)d_in[1];
    const float* bq = (const float*)d_in[2];
    const float* Wk = (const float*)d_in[3];
    const float* bk = (const float*)d_in[4];
    const float* wg = (const float*)d_in[5];
    const float* Wp = (const float*)d_in[6];
    const float* bp = (const float*)d_in[7];
    const float* Wf = (const float*)d_in[8];
    const float* bf = (const float*)d_in[9];
    float* out = (float*)d_out;

    // ws layout (floats): Q[T_*D_], K[T_*D_], QW[T_], G[B_*D_]
    // total = 2*16M + 32K + 16K floats ~= 128.2 MiB
    float* Q  = (float*)d_ws;
    float* K  = Q + (size_t)T_ * D_;
    float* QW = K + (size_t)T_ * D_;
    float* G  = QW + T_;

    const dim3 blk(256);
    const dim3 gg(D_ / BN, T_ / BM);  // (8, 512) col-tile fastest

    // q_raw = x @ Wq^T + bq ; k_raw = x @ Wk^T + bk
    gemm_k<0><<<gg, blk, 0, stream>>>(x, Wq, bq, nullptr, nullptr, Q);
    gemm_k<0><<<gg, blk, 0, stream>>>(x, Wk, bk, nullptr, nullptr, K);
    // row l2norm both; qw = q_norm . w_g
    rownorm_k<<<dim3(T_ / 4, 2), blk, 0, stream>>>(Q, K, wg, QW);
    // fold sequence-axis normalization + scale into qw
    qwscale_k<<<dim3(B_), blk, 0, stream>>>(QW);
    // g = sum_n qw_n * q_n
    hipMemsetAsync(G, 0, B_ * D_ * sizeof(float), stream);
    gctx_k<<<dim3(8, B_), dim3(512), 0, stream>>>(QW, Q, G);
    // out1 = (g (*) key) @ Wp^T + bp + query   (overwrites Q in place; each
    // block reads exactly the Q tile it writes -> race-free)
    gemm_k<1><<<gg, blk, 0, stream>>>(K, Wp, bp, G, Q, Q);
    // out = out1 @ Wf^T + bf, transposed store to [B][C][H*W]
    gemm_k<2><<<gg, blk, 0, stream>>>(Q, Wf, bf, nullptr, nullptr, out);
}

// Round 6
// 193.408 us; speedup vs baseline: 5.3305x; 5.3305x over previous
//
#include <hip/hip_runtime.h>
#include <math.h>

// Problem constants
#define B_ 32
#define D_ 512
#define N_ 1024
#define T_ 32768
#define SCALE 0.04419417382415922f  // 512^-0.5

typedef unsigned short u16;
typedef __attribute__((ext_vector_type(8))) short bf16x8;
typedef __attribute__((ext_vector_type(4))) float f32x4;
typedef __attribute__((ext_vector_type(8))) unsigned short u16x8;

__device__ __forceinline__ u16 bf16_rn(float f) {
    unsigned u = __float_as_uint(f);
    u += 0x7FFFu + ((u >> 16) & 1u);
    return (u16)(u >> 16);
}
__device__ __forceinline__ float bf16f(u16 h) {
    return __uint_as_float(((unsigned)h) << 16);
}

// async global->LDS, 16B/lane; LDS dest = wave-uniform base (+lane*16 by HW)
__device__ __forceinline__ void g2l16(const u16* g, u16* lds) {
    __builtin_amdgcn_global_load_lds(
        (const __attribute__((address_space(1))) unsigned int*)g,
        (__attribute__((address_space(3))) unsigned int*)lds, 16, 0, 0);
}

__device__ __forceinline__ float waveRedSum(float v) {
#pragma unroll
    for (int off = 32; off > 0; off >>= 1) v += __shfl_xor(v, off, 64);
    return v;
}

// ---------------- conversion kernels ----------------

// x [B][C][N] fp32 -> Xbf [T=B*N][C] bf16 (transpose via LDS tile)
__global__ __launch_bounds__(256) void convx_k(const float* __restrict__ x,
                                               u16* __restrict__ X) {
    __shared__ float tile[64][65];
    const int tid = threadIdx.x;
    const int n0 = blockIdx.x * 64, c0 = blockIdx.y * 64, b = blockIdx.z;
    const int nl = tid & 63, cl0 = (tid >> 6) * 16;
#pragma unroll
    for (int j = 0; j < 16; ++j)
        tile[cl0 + j][nl] = x[((size_t)(b * D_ + c0 + cl0 + j) << 10) + n0 + nl];
    __syncthreads();
    const int nr = tid >> 2, cb = (tid & 3) * 16;
    const size_t row = (size_t)(b * N_ + n0 + nr) * D_ + c0 + cb;
    u16 th[16];
#pragma unroll
    for (int j = 0; j < 16; ++j) th[j] = bf16_rn(tile[cb + j][nr]);
    *(u16x8*)&X[row]     = *(const u16x8*)&th[0];
    *(u16x8*)&X[row + 8] = *(const u16x8*)&th[8];
}

// Wq/Wk/Wf [512][512] fp32 -> bf16
__global__ __launch_bounds__(256) void convw_k(const float* __restrict__ W0,
                                               const float* __restrict__ W1,
                                               const float* __restrict__ W2,
                                               u16* O0, u16* O1, u16* O2) {
    const int s = blockIdx.y;
    const float* src = (s == 0) ? W0 : ((s == 1) ? W1 : W2);
    u16* O = (s == 0) ? O0 : ((s == 1) ? O1 : O2);
    const size_t i0 = (size_t)blockIdx.x * 2048 + threadIdx.x * 8;
    u16 o[8];
#pragma unroll
    for (int j = 0; j < 8; ++j) o[j] = bf16_rn(src[i0 + j]);
    *(u16x8*)&O[i0] = *(const u16x8*)&o[0];
}

// WpG[b][e][c] = bf16( Wp[e][c] * g[b][c] )
__global__ __launch_bounds__(256) void scalewp_k(const float* __restrict__ Wp,
                                                 const float* __restrict__ g,
                                                 u16* __restrict__ WpG) {
    const int b = blockIdx.y;
    const size_t f0 = (size_t)blockIdx.x * 2048 + threadIdx.x * 8;
    const int c = (int)(f0 & 511);
    u16 o[8];
#pragma unroll
    for (int j = 0; j < 8; ++j) o[j] = bf16_rn(Wp[f0 + j] * g[b * D_ + c + j]);
    *(u16x8*)&WpG[(size_t)b * 262144 + f0] = *(const u16x8*)&o[0];
}

// ---------------- small math kernels ----------------

// in-place row l2norm on bf16 rows; for Q also qw[row] = q_norm . w_g (fp32)
__global__ __launch_bounds__(256) void rownorm_k(u16* __restrict__ Q,
                                                 u16* __restrict__ K,
                                                 const float* __restrict__ wg,
                                                 float* __restrict__ qw) {
    const int lane = threadIdx.x & 63;
    const int wv = threadIdx.x >> 6;
    const int row = blockIdx.x * 4 + wv;
    const int isK = blockIdx.y;
    u16* base = (isK ? K : Q) + (size_t)row * D_;
    u16x8 v = *(u16x8*)(base + lane * 8);
    float f[8];
    float ss = 0.f;
#pragma unroll
    for (int j = 0; j < 8; ++j) { f[j] = bf16f(v[j]); ss += f[j] * f[j]; }
    ss = waveRedSum(ss);
    const float sc = 1.f / fmaxf(sqrtf(ss), 1e-12f);
    u16 o[8];
#pragma unroll
    for (int j = 0; j < 8; ++j) o[j] = bf16_rn(f[j] * sc);
    *(u16x8*)(base + lane * 8) = *(const u16x8*)&o[0];
    if (!isK) {
        const float4 w0 = *(const float4*)(wg + lane * 8);
        const float4 w1 = *(const float4*)(wg + lane * 8 + 4);
        float d = f[0] * sc * w0.x + f[1] * sc * w0.y + f[2] * sc * w0.z +
                  f[3] * sc * w0.w + f[4] * sc * w1.x + f[5] * sc * w1.y +
                  f[6] * sc * w1.z + f[7] * sc * w1.w;
        d = waveRedSum(d);
        if (lane == 0) qw[row] = d;
    }
}

// per batch: fold sequence-axis l2norm + scale into qw
__global__ __launch_bounds__(256) void qwscale_k(float* __restrict__ qw) {
    __shared__ float red[4];
    const int b = blockIdx.x;
    float* p = qw + (size_t)b * N_ + threadIdx.x * 4;
    float4 v = *(float4*)p;
    float ss = v.x * v.x + v.y * v.y + v.z * v.z + v.w * v.w;
    ss = waveRedSum(ss);
    if ((threadIdx.x & 63) == 0) red[threadIdx.x >> 6] = ss;
    __syncthreads();
    const float S = red[0] + red[1] + red[2] + red[3];
    const float f = SCALE / fmaxf(SCALE * sqrtf(S), 1e-12f);
    v.x *= f; v.y *= f; v.z *= f; v.w *= f;
    *(float4*)p = v;
}

// g[b,d] = sum_n qw[b,n] * Qn[b,n,d]   (Qn bf16)
__global__ __launch_bounds__(512) void gctx_k(const float* __restrict__ qw,
                                              const u16* __restrict__ Qn,
                                              float* __restrict__ g) {
    const int b = blockIdx.y;
    const int n0 = blockIdx.x * 128;
    const int d = threadIdx.x;
    const u16* qp = Qn + ((size_t)b * N_ + n0) * D_ + d;
    const float* wp = qw + (size_t)b * N_ + n0;
    float acc = 0.f;
    for (int n = 0; n < 128; ++n) acc += wp[n] * bf16f(qp[(size_t)n * D_]);
    atomicAdd(g + b * D_ + d, acc);
}

// ---------------- bf16 MFMA GEMM ----------------
// 128x128 tile, BK=64, 4 waves (2x2), 16x16x32 bf16 MFMA, fp32 accum.
// MODE 0: A=Xbf[T][512]; bx<4: B=Wq -> uout0=Qbf, bx>=4: B=Wk -> uout1=Kbf
// MODE 1: A=Kn; B=WpG[batch]; out bf16 IN PLACE over Qn (addend=old value)
// MODE 2: A=Wf rows(e); B=Y rows(t); fp32 transposed store out[b][e][n]
template <int MODE>
__global__ __launch_bounds__(256) void mgemm(
        const u16* __restrict__ A, const u16* __restrict__ B0,
        const u16* __restrict__ B1,
        const float* __restrict__ bias0, const float* __restrict__ bias1,
        float* __restrict__ fout, u16* uout0, u16* uout1) {
    __shared__ u16 As[128 * 64];
    __shared__ u16 Bs[128 * 64];
    const int tid = threadIdx.x;
    const int l = tid & 63, w = tid >> 6;

    int t0, e0, batch = 0;
    const u16* B;
    const float* bias;
    u16* uout = nullptr;
    if (MODE == 0) {
        t0 = blockIdx.y * 128;
        const bool sel = blockIdx.x >= 4;
        e0 = (blockIdx.x & 3) * 128;
        B = sel ? B1 : B0;
        bias = sel ? bias1 : bias0;
        uout = sel ? uout1 : uout0;
    } else if (MODE == 1) {
        t0 = blockIdx.y * 128; e0 = blockIdx.x * 128; batch = blockIdx.y >> 3;
        B = B0 + (size_t)batch * 262144;
        bias = bias0;
        uout = uout0;
    } else {
        t0 = blockIdx.x * 128; e0 = blockIdx.y * 128; batch = blockIdx.x >> 3;
        B = B0;
        bias = bias0;
    }
    const int arow0 = (MODE == 2) ? e0 : t0;
    const int brow0 = (MODE == 2) ? t0 : e0;

    // staging: per wave 4 g2l16 for A and 4 for B; each covers 8 rows x 64 u16.
    // linear LDS dest; SOURCE chunk XOR-swizzled: ch = (l&7)^(row&7)  (rule #21)
    size_t gA[4], gB[4];
    u16 *ldsA[4], *ldsB[4];
#pragma unroll
    for (int i = 0; i < 4; ++i) {
        const int rr = w * 32 + i * 8 + (l >> 3);
        const int ch = (l & 7) ^ (rr & 7);
        gA[i] = (size_t)(arow0 + rr) * 512 + ch * 8;
        gB[i] = (size_t)(brow0 + rr) * 512 + ch * 8;
        ldsA[i] = As + (w * 32 + i * 8) * 64;
        ldsB[i] = Bs + (w * 32 + i * 8) * 64;
    }

    // fragment read offsets (u16 units); reader applies the same XOR
    const int wr = w >> 1, wc = w & 1, kg = l >> 4, r16 = l & 15;
    int aoff[4][2], boff[4][2];
#pragma unroll
    for (int f = 0; f < 4; ++f)
#pragma unroll
        for (int h = 0; h < 2; ++h) {
            const int ra = wr * 64 + f * 16 + r16;
            aoff[f][h] = ra * 64 + (((h * 4 + kg) ^ (ra & 7)) * 8);
            const int rb = wc * 64 + f * 16 + r16;
            boff[f][h] = rb * 64 + (((h * 4 + kg) ^ (rb & 7)) * 8);
        }

    f32x4 acc[4][4];
#pragma unroll
    for (int i = 0; i < 4; ++i)
#pragma unroll
        for (int j = 0; j < 4; ++j) acc[i][j] = 0.f;

#pragma unroll 1
    for (int c0 = 0; c0 < 512; c0 += 64) {
        __syncthreads();  // prior tile fully consumed
#pragma unroll
        for (int i = 0; i < 4; ++i) {
            g2l16(A + gA[i] + c0, ldsA[i]);
            g2l16(B + gB[i] + c0, ldsB[i]);
        }
        __syncthreads();  // vmcnt(0) drain -> LDS ready
#pragma unroll
        for (int h = 0; h < 2; ++h) {
            bf16x8 av[4], bv[4];
#pragma unroll
            for (int f = 0; f < 4; ++f) {
                av[f] = *(const bf16x8*)&As[aoff[f][h]];
                bv[f] = *(const bf16x8*)&Bs[boff[f][h]];
            }
#pragma unroll
            for (int i = 0; i < 4; ++i)
#pragma unroll
                for (int j = 0; j < 4; ++j)
                    acc[i][j] = __builtin_amdgcn_mfma_f32_16x16x32_bf16(
                        av[i], bv[j], acc[i][j], 0, 0, 0);
        }
    }

    // epilogue: C/D layout col = lane&15, row = (lane>>4)*4 + reg  [m89]
    const int mb = wr * 64 + kg * 4;
    const int nb = wc * 64 + r16;
    if (MODE == 2) {
#pragma unroll
        for (int fm = 0; fm < 4; ++fm)
#pragma unroll
            for (int fn = 0; fn < 4; ++fn) {
                const int ntok = (t0 & 1023) + nb + fn * 16;
#pragma unroll
                for (int q = 0; q < 4; ++q) {
                    const int e = e0 + mb + fm * 16 + q;
                    fout[((size_t)(batch * D_ + e) << 10) + ntok] =
                        acc[fm][fn][q] + bias[e];
                }
            }
    } else {
#pragma unroll
        for (int fm = 0; fm < 4; ++fm)
#pragma unroll
            for (int fn = 0; fn < 4; ++fn) {
                const int n = e0 + nb + fn * 16;
                const float bb = bias[n];
#pragma unroll
                for (int q = 0; q < 4; ++q) {
                    const int m = t0 + mb + fm * 16 + q;
                    const size_t idx = (size_t)m * 512 + n;
                    float val = acc[fm][fn][q] + bb;
                    if (MODE == 1) val += bf16f(uout[idx]);  // +query, in place
                    uout[idx] = bf16_rn(val);
                }
            }
    }
}

// ---------------- launcher ----------------

extern "C" void kernel_launch(void* const* d_in, const int* in_sizes, int n_in,
                              void* d_out, int out_size, void* d_ws, size_t ws_size,
                              hipStream_t stream) {
    const float* x  = (const float*)d_in[0];
    const float* Wq = (const float*)d_in[1];
    const float* bq = (const float*)d_in[2];
    const float* Wk = (const float*)d_in[3];
    const float* bk = (const float*)d_in[4];
    const float* wg = (const float*)d_in[5];
    const float* Wp = (const float*)d_in[6];
    const float* bp = (const float*)d_in[7];
    const float* Wf = (const float*)d_in[8];
    const float* bf = (const float*)d_in[9];
    float* out = (float*)d_out;

    // ws map (bytes), peak ~98.4 MB (proven budget: >=128.2 MB from round 4):
    // [0,32M)   Xbf   (dead after mgemm<0>)  -> [0,16M) WpG (from scalewp on)
    // [32M,64M) Qbf -> Qn (rownorm in place) -> Y (mgemm<1> in place)
    // [64M,96M) Kbf -> Kn (rownorm in place)
    // [96M,..)  Wqbf, Wkbf, Wfbf, QW, G
    char* Wb = (char*)d_ws;
    u16* Xbf = (u16*)Wb;
    u16* WpG = (u16*)Wb;
    u16* Qn  = (u16*)(Wb + 33554432ull);
    u16* Kn  = (u16*)(Wb + 67108864ull);
    char* S  = Wb + 100663296ull;
    u16* Wqbf = (u16*)S;
    u16* Wkbf = (u16*)(S + 524288ull);
    u16* Wfbf = (u16*)(S + 1048576ull);
    float* QW = (float*)(S + 1572864ull);
    float* G  = (float*)(S + 1703936ull);

    const dim3 blk(256);

    // 1. x -> Xbf (token-major bf16)
    convx_k<<<dim3(16, 8, 32), blk, 0, stream>>>(x, Xbf);
    // 2. weights -> bf16
    convw_k<<<dim3(128, 3), blk, 0, stream>>>(Wq, Wk, Wf, Wqbf, Wkbf, Wfbf);
    // 3. fused q/k projection -> Qbf, Kbf (bf16)
    mgemm<0><<<dim3(8, 256), blk, 0, stream>>>(Xbf, Wqbf, Wkbf, bq, bk,
                                               nullptr, Qn, Kn);
    // 4. in-place row l2norm; qw = query . w_g
    rownorm_k<<<dim3(T_ / 4, 2), blk, 0, stream>>>(Qn, Kn, wg, QW);
    // 5. fold sequence-axis normalization + scale into qw
    qwscale_k<<<dim3(B_), blk, 0, stream>>>(QW);
    // 6. g = sum_n qw_n * query_n
    hipMemsetAsync(G, 0, B_ * D_ * sizeof(float), stream);
    gctx_k<<<dim3(8, B_), dim3(512), 0, stream>>>(QW, Qn, G);
    // 7. WpG[b] = Wp * g[b]
    scalewp_k<<<dim3(128, B_), blk, 0, stream>>>(Wp, G, WpG);
    // 8. Y = key @ WpG[b]^T + bp + query  (bf16, in place over Qn)
    mgemm<1><<<dim3(4, 256), blk, 0, stream>>>(Kn, WpG, nullptr, bp, nullptr,
                                               nullptr, Qn, nullptr);
    // 9. out[b][e][n] = Wf x Y^T + bf  (fp32, final layout)
    mgemm<2><<<dim3(256, 4), blk, 0, stream>>>(Wfbf, Qn, nullptr, bf, nullptr,
                                               out, nullptr, nullptr);
}

// Round 8
// 171.757 us; speedup vs baseline: 6.0025x; 1.1261x over previous
//
#include <hip/hip_runtime.h>
#include <math.h>

// Problem constants
#define B_ 32
#define D_ 512
#define N_ 1024
#define T_ 32768
#define SCALE 0.04419417382415922f  // 512^-0.5

typedef unsigned short u16;
typedef __attribute__((ext_vector_type(8))) short bf16x8;
typedef __attribute__((ext_vector_type(4))) float f32x4;
typedef __attribute__((ext_vector_type(8))) unsigned short u16x8;

__device__ __forceinline__ u16 bf16_rn(float f) {
    unsigned u = __float_as_uint(f);
    u += 0x7FFFu + ((u >> 16) & 1u);
    return (u16)(u >> 16);
}
__device__ __forceinline__ float bf16f(u16 h) {
    return __uint_as_float(((unsigned)h) << 16);
}

// async global->LDS, 16B/lane; LDS dest = wave-uniform base (+lane*16 by HW)
__device__ __forceinline__ void g2l16(const u16* g, u16* lds) {
    __builtin_amdgcn_global_load_lds(
        (const __attribute__((address_space(1))) unsigned int*)g,
        (__attribute__((address_space(3))) unsigned int*)lds, 16, 0, 0);
}

__device__ __forceinline__ float waveRedSum(float v) {
#pragma unroll
    for (int off = 32; off > 0; off >>= 1) v += __shfl_xor(v, off, 64);
    return v;
}

// ---------------- conversion kernels ----------------

// x [B][C][N] fp32 -> Xbf [T=B*N][C] bf16 (transpose via LDS tile)
__global__ __launch_bounds__(256) void convx_k(const float* __restrict__ x,
                                               u16* __restrict__ X) {
    __shared__ float tile[64][65];
    const int tid = threadIdx.x;
    const int n0 = blockIdx.x * 64, c0 = blockIdx.y * 64, b = blockIdx.z;
    const int nl = tid & 63, cl0 = (tid >> 6) * 16;
#pragma unroll
    for (int j = 0; j < 16; ++j)
        tile[cl0 + j][nl] = x[((size_t)(b * D_ + c0 + cl0 + j) << 10) + n0 + nl];
    __syncthreads();
    const int nr = tid >> 2, cb = (tid & 3) * 16;
    const size_t row = (size_t)(b * N_ + n0 + nr) * D_ + c0 + cb;
    u16 th[16];
#pragma unroll
    for (int j = 0; j < 16; ++j) th[j] = bf16_rn(tile[cb + j][nr]);
    *(u16x8*)&X[row]     = *(const u16x8*)&th[0];
    *(u16x8*)&X[row + 8] = *(const u16x8*)&th[8];
}

// Wq/Wk/Wf [512][512] fp32 -> bf16
__global__ __launch_bounds__(256) void convw_k(const float* __restrict__ W0,
                                               const float* __restrict__ W1,
                                               const float* __restrict__ W2,
                                               u16* O0, u16* O1, u16* O2) {
    const int s = blockIdx.y;
    const float* src = (s == 0) ? W0 : ((s == 1) ? W1 : W2);
    u16* O = (s == 0) ? O0 : ((s == 1) ? O1 : O2);
    const size_t i0 = (size_t)blockIdx.x * 2048 + threadIdx.x * 8;
    u16 o[8];
#pragma unroll
    for (int j = 0; j < 8; ++j) o[j] = bf16_rn(src[i0 + j]);
    *(u16x8*)&O[i0] = *(const u16x8*)&o[0];
}

// WpG[b][e][c] = bf16( Wp[e][c] * g[b][c] )
__global__ __launch_bounds__(256) void scalewp_k(const float* __restrict__ Wp,
                                                 const float* __restrict__ g,
                                                 u16* __restrict__ WpG) {
    const int b = blockIdx.y;
    const size_t f0 = (size_t)blockIdx.x * 2048 + threadIdx.x * 8;
    const int c = (int)(f0 & 511);
    u16 o[8];
#pragma unroll
    for (int j = 0; j < 8; ++j) o[j] = bf16_rn(Wp[f0 + j] * g[b * D_ + c + j]);
    *(u16x8*)&WpG[(size_t)b * 262144 + f0] = *(const u16x8*)&o[0];
}

// ---------------- small math kernels ----------------

// in-place row l2norm on bf16 rows; for Q also qw[row] = q_norm . w_g (fp32)
__global__ __launch_bounds__(256) void rownorm_k(u16* __restrict__ Q,
                                                 u16* __restrict__ K,
                                                 const float* __restrict__ wg,
                                                 float* __restrict__ qw) {
    const int lane = threadIdx.x & 63;
    const int wv = threadIdx.x >> 6;
    const int row = blockIdx.x * 4 + wv;
    const int isK = blockIdx.y;
    u16* base = (isK ? K : Q) + (size_t)row * D_;
    u16x8 v = *(u16x8*)(base + lane * 8);
    float f[8];
    float ss = 0.f;
#pragma unroll
    for (int j = 0; j < 8; ++j) { f[j] = bf16f(v[j]); ss += f[j] * f[j]; }
    ss = waveRedSum(ss);
    const float sc = 1.f / fmaxf(sqrtf(ss), 1e-12f);
    u16 o[8];
#pragma unroll
    for (int j = 0; j < 8; ++j) o[j] = bf16_rn(f[j] * sc);
    *(u16x8*)(base + lane * 8) = *(const u16x8*)&o[0];
    if (!isK) {
        const float4 w0 = *(const float4*)(wg + lane * 8);
        const float4 w1 = *(const float4*)(wg + lane * 8 + 4);
        float d = f[0] * sc * w0.x + f[1] * sc * w0.y + f[2] * sc * w0.z +
                  f[3] * sc * w0.w + f[4] * sc * w1.x + f[5] * sc * w1.y +
                  f[6] * sc * w1.z + f[7] * sc * w1.w;
        d = waveRedSum(d);
        if (lane == 0) qw[row] = d;
    }
}

// per batch: fold sequence-axis l2norm + scale into qw
__global__ __launch_bounds__(256) void qwscale_k(float* __restrict__ qw) {
    __shared__ float red[4];
    const int b = blockIdx.x;
    float* p = qw + (size_t)b * N_ + threadIdx.x * 4;
    float4 v = *(float4*)p;
    float ss = v.x * v.x + v.y * v.y + v.z * v.z + v.w * v.w;
    ss = waveRedSum(ss);
    if ((threadIdx.x & 63) == 0) red[threadIdx.x >> 6] = ss;
    __syncthreads();
    const float S = red[0] + red[1] + red[2] + red[3];
    const float f = SCALE / fmaxf(SCALE * sqrtf(S), 1e-12f);
    v.x *= f; v.y *= f; v.z *= f; v.w *= f;
    *(float4*)p = v;
}

// g[b,d] = sum_n qw[b,n] * Qn[b,n,d]   (Qn bf16)
__global__ __launch_bounds__(512) void gctx_k(const float* __restrict__ qw,
                                              const u16* __restrict__ Qn,
                                              float* __restrict__ g) {
    const int b = blockIdx.y;
    const int n0 = blockIdx.x * 128;
    const int d = threadIdx.x;
    const u16* qp = Qn + ((size_t)b * N_ + n0) * D_ + d;
    const float* wp = qw + (size_t)b * N_ + n0;
    float acc = 0.f;
    for (int n = 0; n < 128; ++n) acc += wp[n] * bf16f(qp[(size_t)n * D_]);
    atomicAdd(g + b * D_ + d, acc);
}

// ---------------- bf16 MFMA GEMM ----------------
// Tile 128(M) x 256(N), BK=64, 8 waves (2x4 of 64x64), 16x16x32 bf16 MFMA.
// 1-D grid, XCD-swizzled decode: all blocks sharing an A row-panel map to the
// same launched_id%8 (same XCD) so the panel is L2-resident after first touch.
// MODE 0: A=Xbf[T][512]; bx<2: B=Wq -> Qn, bx>=2: B=Wk -> Kn  (nwg=1024)
// MODE 1: A=Kn; B=WpG[batch]; bf16 in place over Qn (+query)  (nwg=512)
// MODE 2: A=Wf rows(e, M=128); B=Y rows(t, N=256); fp32 transposed
//         store out[b][e][n]                                   (nwg=512)
template <int MODE>
__global__ __launch_bounds__(512) void mgemm(
        const u16* __restrict__ A, const u16* __restrict__ B0,
        const u16* __restrict__ B1,
        const float* __restrict__ bias0, const float* __restrict__ bias1,
        float* __restrict__ fout, u16* uout0, u16* uout1) {
    __shared__ u16 As[128 * 64];
    __shared__ u16 Bs[256 * 64];
    const int tid = threadIdx.x;
    const int l = tid & 63, w = tid >> 6;
    const int gid = blockIdx.x;
    const int xcd = gid & 7;

    int t0, e0, batch = 0;
    const u16* B;
    const float* bias;
    u16* uout = nullptr;
    if (MODE == 0) {
        const int bx = (gid >> 3) & 3;           // col tile (shares A panel)
        const int by = (gid >> 5) * 8 + xcd;     // row tile -> fixed XCD
        t0 = by * 128;
        const bool sel = bx >= 2;
        e0 = (bx & 1) * 256;
        B = sel ? B1 : B0;
        bias = sel ? bias1 : bias0;
        uout = sel ? uout1 : uout0;
    } else if (MODE == 1) {
        const int bx = (gid >> 3) & 1;
        const int by = (gid >> 4) * 8 + xcd;
        t0 = by * 128; e0 = bx * 256; batch = by >> 3;
        B = B0 + (size_t)batch * 262144;
        bias = bias0;
        uout = uout0;
    } else {
        const int by = (gid >> 3) & 3;           // e tile
        const int bx = (gid >> 5) * 8 + xcd;     // token tile (shares B panel)
        t0 = bx * 256; e0 = by * 128; batch = bx >> 2;
        B = B0;
        bias = bias0;
    }
    const int arow0 = (MODE == 2) ? e0 : t0;     // A: M rows
    const int brow0 = (MODE == 2) ? t0 : e0;     // B: N rows

    // staging: per wave 2 g2l16 for A (16 rows) + 4 for B (32 rows);
    // linear LDS dest; SOURCE chunk XOR-swizzled: ch = (l&7)^(row&7) (rule #21)
    size_t gA[2], gB[4];
    u16 *ldsA[2], *ldsB[4];
#pragma unroll
    for (int i = 0; i < 2; ++i) {
        const int rr = w * 16 + i * 8 + (l >> 3);
        gA[i] = (size_t)(arow0 + rr) * 512 + (((l & 7) ^ (rr & 7)) * 8);
        ldsA[i] = As + (w * 16 + i * 8) * 64;
    }
#pragma unroll
    for (int i = 0; i < 4; ++i) {
        const int rr = w * 32 + i * 8 + (l >> 3);
        gB[i] = (size_t)(brow0 + rr) * 512 + (((l & 7) ^ (rr & 7)) * 8);
        ldsB[i] = Bs + (w * 32 + i * 8) * 64;
    }

    // fragment read offsets (u16 units); reader applies the same XOR
    const int wr = w >> 2, wc = w & 3, kg = l >> 4, r16 = l & 15;
    int aoff[4][2], boff[4][2];
#pragma unroll
    for (int f = 0; f < 4; ++f)
#pragma unroll
        for (int h = 0; h < 2; ++h) {
            const int ra = wr * 64 + f * 16 + r16;
            aoff[f][h] = ra * 64 + (((h * 4 + kg) ^ (ra & 7)) * 8);
            const int rb = wc * 64 + f * 16 + r16;
            boff[f][h] = rb * 64 + (((h * 4 + kg) ^ (rb & 7)) * 8);
        }

    f32x4 acc[4][4];
#pragma unroll
    for (int i = 0; i < 4; ++i)
#pragma unroll
        for (int j = 0; j < 4; ++j) acc[i][j] = 0.f;

#pragma unroll 1
    for (int c0 = 0; c0 < 512; c0 += 64) {
        __syncthreads();  // prior tile fully consumed
#pragma unroll
        for (int i = 0; i < 2; ++i) g2l16(A + gA[i] + c0, ldsA[i]);
#pragma unroll
        for (int i = 0; i < 4; ++i) g2l16(B + gB[i] + c0, ldsB[i]);
        __syncthreads();  // vmcnt(0) drain -> LDS ready
#pragma unroll
        for (int h = 0; h < 2; ++h) {
            bf16x8 av[4], bv[4];
#pragma unroll
            for (int f = 0; f < 4; ++f) {
                av[f] = *(const bf16x8*)&As[aoff[f][h]];
                bv[f] = *(const bf16x8*)&Bs[boff[f][h]];
            }
#pragma unroll
            for (int i = 0; i < 4; ++i)
#pragma unroll
                for (int j = 0; j < 4; ++j)
                    acc[i][j] = __builtin_amdgcn_mfma_f32_16x16x32_bf16(
                        av[i], bv[j], acc[i][j], 0, 0, 0);
        }
    }

    // epilogue: C/D layout col = lane&15, row = (lane>>4)*4 + reg  [m89]
    const int mb = wr * 64 + kg * 4;
    const int nb = wc * 64 + r16;
    if (MODE == 2) {
#pragma unroll
        for (int fm = 0; fm < 4; ++fm)
#pragma unroll
            for (int fn = 0; fn < 4; ++fn) {
                const int ntok = (t0 & 1023) + nb + fn * 16;
#pragma unroll
                for (int q = 0; q < 4; ++q) {
                    const int e = e0 + mb + fm * 16 + q;
                    fout[((size_t)(batch * D_ + e) << 10) + ntok] =
                        acc[fm][fn][q] + bias[e];
                }
            }
    } else {
#pragma unroll
        for (int fm = 0; fm < 4; ++fm)
#pragma unroll
            for (int fn = 0; fn < 4; ++fn) {
                const int n = e0 + nb + fn * 16;
                const float bb = bias[n];
#pragma unroll
                for (int q = 0; q < 4; ++q) {
                    const int m = t0 + mb + fm * 16 + q;
                    const size_t idx = (size_t)m * 512 + n;
                    float val = acc[fm][fn][q] + bb;
                    if (MODE == 1) val += bf16f(uout[idx]);  // +query, in place
                    uout[idx] = bf16_rn(val);
                }
            }
    }
}

// ---------------- launcher ----------------

extern "C" void kernel_launch(void* const* d_in, const int* in_sizes, int n_in,
                              void* d_out, int out_size, void* d_ws, size_t ws_size,
                              hipStream_t stream) {
    const float* x  = (const float*)d_in[0];
    const float* Wq = (const float*)d_in[1];
    const float* bq = (const float*)d_in[2];
    const float* Wk = (const float*)d_in[3];
    const float* bk = (const float*)d_in[4];
    const float* wg = (const float*)d_in[5];
    const float* Wp = (const float*)d_in[6];
    const float* bp = (const float*)d_in[7];
    const float* Wf = (const float*)d_in[8];
    const float* bf = (const float*)d_in[9];
    float* out = (float*)d_out;

    // ws map (bytes), peak ~98.4 MB:
    // [0,32M)   Xbf   (dead after mgemm<0>)  -> [0,16M) WpG (from scalewp on)
    // [32M,64M) Qbf -> Qn (rownorm in place) -> Y (mgemm<1> in place)
    // [64M,96M) Kbf -> Kn (rownorm in place)
    // [96M,..)  Wqbf, Wkbf, Wfbf, QW, G
    char* Wb = (char*)d_ws;
    u16* Xbf = (u16*)Wb;
    u16* WpG = (u16*)Wb;
    u16* Qn  = (u16*)(Wb + 33554432ull);
    u16* Kn  = (u16*)(Wb + 67108864ull);
    char* S  = Wb + 100663296ull;
    u16* Wqbf = (u16*)S;
    u16* Wkbf = (u16*)(S + 524288ull);
    u16* Wfbf = (u16*)(S + 1048576ull);
    float* QW = (float*)(S + 1572864ull);
    float* G  = (float*)(S + 1703936ull);

    const dim3 blk(256);

    // 1. x -> Xbf (token-major bf16)
    convx_k<<<dim3(16, 8, 32), blk, 0, stream>>>(x, Xbf);
    // 2. weights -> bf16
    convw_k<<<dim3(128, 3), blk, 0, stream>>>(Wq, Wk, Wf, Wqbf, Wkbf, Wfbf);
    // 3. fused q/k projection -> Qbf, Kbf (bf16)
    mgemm<0><<<dim3(1024), dim3(512), 0, stream>>>(Xbf, Wqbf, Wkbf, bq, bk,
                                                   nullptr, Qn, Kn);
    // 4. in-place row l2norm; qw = query . w_g
    rownorm_k<<<dim3(T_ / 4, 2), blk, 0, stream>>>(Qn, Kn, wg, QW);
    // 5. fold sequence-axis normalization + scale into qw
    qwscale_k<<<dim3(B_), blk, 0, stream>>>(QW);
    // 6. g = sum_n qw_n * query_n
    hipMemsetAsync(G, 0, B_ * D_ * sizeof(float), stream);
    gctx_k<<<dim3(8, B_), dim3(512), 0, stream>>>(QW, Qn, G);
    // 7. WpG[b] = Wp * g[b]
    scalewp_k<<<dim3(128, B_), blk, 0, stream>>>(Wp, G, WpG);
    // 8. Y = key @ WpG[b]^T + bp + query  (bf16, in place over Qn)
    mgemm<1><<<dim3(512), dim3(512), 0, stream>>>(Kn, WpG, nullptr, bp, nullptr,
                                                  nullptr, Qn, nullptr);
    // 9. out[b][e][n] = Wf x Y^T + bf  (fp32, final layout)
    mgemm<2><<<dim3(512), dim3(512), 0, stream>>>(Wfbf, Qn, nullptr, bf, nullptr,
                                                  out, nullptr, nullptr);
}

// Round 9
// 157.146 us; speedup vs baseline: 6.5606x; 1.0930x over previous
//
#include <hip/hip_runtime.h>
#include <math.h>

// Problem constants
#define B_ 32
#define D_ 512
#define N_ 1024
#define T_ 32768
#define SCALE 0.04419417382415922f  // 512^-0.5

typedef unsigned short u16;
typedef __attribute__((ext_vector_type(8))) short bf16x8;
typedef __attribute__((ext_vector_type(4))) float f32x4;
typedef __attribute__((ext_vector_type(8))) unsigned short u16x8;

__device__ __forceinline__ u16 bf16_rn(float f) {
    unsigned u = __float_as_uint(f);
    u += 0x7FFFu + ((u >> 16) & 1u);
    return (u16)(u >> 16);
}
__device__ __forceinline__ float bf16f(u16 h) {
    return __uint_as_float(((unsigned)h) << 16);
}

// async global->LDS, 16B/lane; LDS dest = wave-uniform base (+lane*16 by HW)
__device__ __forceinline__ void g2l16(const u16* g, u16* lds) {
    __builtin_amdgcn_global_load_lds(
        (const __attribute__((address_space(1))) unsigned int*)g,
        (__attribute__((address_space(3))) unsigned int*)lds, 16, 0, 0);
}

__device__ __forceinline__ float waveRedSum(float v) {
#pragma unroll
    for (int off = 32; off > 0; off >>= 1) v += __shfl_xor(v, off, 64);
    return v;
}

// ---------------- conversion kernels ----------------

// x [B][C][N] fp32 -> Xbf [T=B*N][C] bf16 (transpose via LDS tile)
__global__ __launch_bounds__(256) void convx_k(const float* __restrict__ x,
                                               u16* __restrict__ X) {
    __shared__ float tile[64][65];
    const int tid = threadIdx.x;
    const int n0 = blockIdx.x * 64, c0 = blockIdx.y * 64, b = blockIdx.z;
    const int nl = tid & 63, cl0 = (tid >> 6) * 16;
#pragma unroll
    for (int j = 0; j < 16; ++j)
        tile[cl0 + j][nl] = x[((size_t)(b * D_ + c0 + cl0 + j) << 10) + n0 + nl];
    __syncthreads();
    const int nr = tid >> 2, cb = (tid & 3) * 16;
    const size_t row = (size_t)(b * N_ + n0 + nr) * D_ + c0 + cb;
    u16 th[16];
#pragma unroll
    for (int j = 0; j < 16; ++j) th[j] = bf16_rn(tile[cb + j][nr]);
    *(u16x8*)&X[row]     = *(const u16x8*)&th[0];
    *(u16x8*)&X[row + 8] = *(const u16x8*)&th[8];
}

// Wq/Wk/Wf [512][512] fp32 -> bf16
__global__ __launch_bounds__(256) void convw_k(const float* __restrict__ W0,
                                               const float* __restrict__ W1,
                                               const float* __restrict__ W2,
                                               u16* O0, u16* O1, u16* O2) {
    const int s = blockIdx.y;
    const float* src = (s == 0) ? W0 : ((s == 1) ? W1 : W2);
    u16* O = (s == 0) ? O0 : ((s == 1) ? O1 : O2);
    const size_t i0 = (size_t)blockIdx.x * 2048 + threadIdx.x * 8;
    u16 o[8];
#pragma unroll
    for (int j = 0; j < 8; ++j) o[j] = bf16_rn(src[i0 + j]);
    *(u16x8*)&O[i0] = *(const u16x8*)&o[0];
}

// ---------------- small math kernels ----------------

// finalize per-row norms: ssqQ/ssqK -> rscale (in place), qwr -> gctx coeff
// c_n = (raw.wg)*rsQ^2 ; Sb[b] += (qw')^2 where qw' = (raw.wg)*rsQ
__global__ __launch_bounds__(256) void finalize_k(float* __restrict__ ssqQ,
                                                  float* __restrict__ ssqK,
                                                  float* __restrict__ qwr,
                                                  float* __restrict__ Sb) {
    __shared__ float red[4];
    const int i = blockIdx.x * 256 + threadIdx.x;
    const float rq = 1.f / fmaxf(sqrtf(ssqQ[i]), 1e-12f);
    ssqQ[i] = rq;
    const float rk = 1.f / fmaxf(sqrtf(ssqK[i]), 1e-12f);
    ssqK[i] = rk;
    const float qwp = qwr[i] * rq;   // normalized-q dot wg
    qwr[i] = qwp * rq;               // coefficient for gctx (extra rsQ for q-hat)
    float s = qwp * qwp;
    s = waveRedSum(s);
    if ((threadIdx.x & 63) == 0) red[threadIdx.x >> 6] = s;
    __syncthreads();
    if (threadIdx.x == 0)
        atomicAdd(Sb + (blockIdx.x >> 2), red[0] + red[1] + red[2] + red[3]);
}

// graw[b,d] = sum_n coeff[b,n] * Qraw[b,n,d]
__global__ __launch_bounds__(512) void gctx_k(const float* __restrict__ qw,
                                              const u16* __restrict__ Qn,
                                              float* __restrict__ g) {
    const int b = blockIdx.y;
    const int n0 = blockIdx.x * 128;
    const int d = threadIdx.x;
    const u16* qp = Qn + ((size_t)b * N_ + n0) * D_ + d;
    const float* wp = qw + (size_t)b * N_ + n0;
    float acc = 0.f;
    for (int n = 0; n < 128; ++n) acc += wp[n] * bf16f(qp[(size_t)n * D_]);
    atomicAdd(g + b * D_ + d, acc);
}

// WpG[b][e][c] = bf16( Wp[e][c] * graw[b][c] * f_b ),  f_b from Sb
__global__ __launch_bounds__(256) void scalewp_k(const float* __restrict__ Wp,
                                                 const float* __restrict__ g,
                                                 const float* __restrict__ Sb,
                                                 u16* __restrict__ WpG) {
    const int b = blockIdx.y;
    const float fb = SCALE / fmaxf(SCALE * sqrtf(Sb[b]), 1e-12f);
    const size_t f0 = (size_t)blockIdx.x * 2048 + threadIdx.x * 8;
    const int c = (int)(f0 & 511);
    u16 o[8];
#pragma unroll
    for (int j = 0; j < 8; ++j)
        o[j] = bf16_rn(Wp[f0 + j] * g[b * D_ + c + j] * fb);
    *(u16x8*)&WpG[(size_t)b * 262144 + f0] = *(const u16x8*)&o[0];
}

// ---------------- GEMM 0: q/k projection, fused norm-stats ----------------
// Tile 128(M)x256(N), BK=64, 8 waves (2x4), 16x16x32 bf16 MFMA, XCD-swizzled.
// Stores RAW (biased) Q/K bf16 + atomicAdd per-row sumsq (ssqQ/ssqK) and
// raw.wg dot partials (qwr, Q only).
__global__ __launch_bounds__(512) void mgemm0(
        const u16* __restrict__ A, const u16* __restrict__ B0,
        const u16* __restrict__ B1,
        const float* __restrict__ bias0, const float* __restrict__ bias1,
        const float* __restrict__ wg,
        float* __restrict__ ssqQ, float* __restrict__ ssqK,
        float* __restrict__ qwr, u16* uout0, u16* uout1) {
    __shared__ u16 As[128 * 64];
    __shared__ u16 Bs[256 * 64];
    const int tid = threadIdx.x;
    const int l = tid & 63, w = tid >> 6;
    const int gid = blockIdx.x;
    const int xcd = gid & 7;
    const int bx = (gid >> 3) & 3;           // col tile (shares A panel)
    const int by = (gid >> 5) * 8 + xcd;     // row tile -> fixed XCD
    const int t0 = by * 128;
    const bool sel = bx >= 2;                // false: Q, true: K
    const int e0 = (bx & 1) * 256;
    const u16* B = sel ? B1 : B0;
    const float* bias = sel ? bias1 : bias0;
    u16* uout = sel ? uout1 : uout0;
    float* ssq = sel ? ssqK : ssqQ;

    size_t gA[2], gB[4];
    u16 *ldsA[2], *ldsB[4];
#pragma unroll
    for (int i = 0; i < 2; ++i) {
        const int rr = w * 16 + i * 8 + (l >> 3);
        gA[i] = (size_t)(t0 + rr) * 512 + (((l & 7) ^ (rr & 7)) * 8);
        ldsA[i] = As + (w * 16 + i * 8) * 64;
    }
#pragma unroll
    for (int i = 0; i < 4; ++i) {
        const int rr = w * 32 + i * 8 + (l >> 3);
        gB[i] = (size_t)(e0 + rr) * 512 + (((l & 7) ^ (rr & 7)) * 8);
        ldsB[i] = Bs + (w * 32 + i * 8) * 64;
    }

    const int wr = w >> 2, wc = w & 3, kg = l >> 4, r16 = l & 15;
    int aoff[4][2], boff[4][2];
#pragma unroll
    for (int f = 0; f < 4; ++f)
#pragma unroll
        for (int h = 0; h < 2; ++h) {
            const int ra = wr * 64 + f * 16 + r16;
            aoff[f][h] = ra * 64 + (((h * 4 + kg) ^ (ra & 7)) * 8);
            const int rb = wc * 64 + f * 16 + r16;
            boff[f][h] = rb * 64 + (((h * 4 + kg) ^ (rb & 7)) * 8);
        }

    f32x4 acc[4][4];
#pragma unroll
    for (int i = 0; i < 4; ++i)
#pragma unroll
        for (int j = 0; j < 4; ++j) acc[i][j] = 0.f;

#pragma unroll 1
    for (int c0 = 0; c0 < 512; c0 += 64) {
        __syncthreads();
#pragma unroll
        for (int i = 0; i < 2; ++i) g2l16(A + gA[i] + c0, ldsA[i]);
#pragma unroll
        for (int i = 0; i < 4; ++i) g2l16(B + gB[i] + c0, ldsB[i]);
        __syncthreads();
#pragma unroll
        for (int h = 0; h < 2; ++h) {
            bf16x8 av[4], bv[4];
#pragma unroll
            for (int f = 0; f < 4; ++f) {
                av[f] = *(const bf16x8*)&As[aoff[f][h]];
                bv[f] = *(const bf16x8*)&Bs[boff[f][h]];
            }
#pragma unroll
            for (int i = 0; i < 4; ++i)
#pragma unroll
                for (int j = 0; j < 4; ++j)
                    acc[i][j] = __builtin_amdgcn_mfma_f32_16x16x32_bf16(
                        av[i], bv[j], acc[i][j], 0, 0, 0);
        }
    }

    // epilogue: raw store + row sumsq / wg-dot partials
    const int mb = wr * 64 + kg * 4;
    const int nb = wc * 64 + r16;
    float bb[4], wgv[4];
#pragma unroll
    for (int fn = 0; fn < 4; ++fn) {
        const int n = e0 + nb + fn * 16;
        bb[fn] = bias[n];
        wgv[fn] = sel ? 0.f : wg[n];
    }
#pragma unroll
    for (int fm = 0; fm < 4; ++fm) {
#pragma unroll
        for (int q = 0; q < 4; ++q) {
            const int m = t0 + mb + fm * 16 + q;
            float s2 = 0.f, wd = 0.f;
#pragma unroll
            for (int fn = 0; fn < 4; ++fn) {
                const float val = acc[fm][fn][q] + bb[fn];
                uout[(size_t)m * 512 + e0 + nb + fn * 16] = bf16_rn(val);
                s2 += val * val;
                wd += val * wgv[fn];
            }
#pragma unroll
            for (int off = 1; off < 16; off <<= 1) {
                s2 += __shfl_xor(s2, off, 64);
                wd += __shfl_xor(wd, off, 64);
            }
            if (r16 == 0) {
                atomicAdd(ssq + m, s2);
                if (!sel) atomicAdd(qwr + m, wd);
            }
        }
    }
}

// ---------------- GEMM 1/2: 128x128, 4 waves, XCD-swizzled ----------------
// MODE 1: A=Kraw; B=WpG[batch]; out bf16 in place over Qraw:
//         val = acc*rsK[m] + bp[n] + qraw*rsQ[m]
// MODE 2: A=Wf rows(e); B=Y rows(t); fp32 transposed store out[b][e][n]
template <int MODE>
__global__ __launch_bounds__(256) void mgemm12(
        const u16* __restrict__ A, const u16* __restrict__ B0,
        const float* __restrict__ bias,
        const float* __restrict__ rsA, const float* __restrict__ rsQ,
        u16* uout, float* __restrict__ fout) {
    __shared__ u16 As[128 * 64];
    __shared__ u16 Bs[128 * 64];
    const int tid = threadIdx.x;
    const int l = tid & 63, w = tid >> 6;
    const int gid = blockIdx.x;
    const int xcd = gid & 7;
    const int col = (gid >> 3) & 3;          // shares the 'rowt' panel
    const int rowt = (gid >> 5) * 8 + xcd;   // [0,256) token tile -> fixed XCD

    const int t0 = rowt * 128 * (MODE == 1 ? 1 : 2) / (MODE == 1 ? 1 : 2);
    const int tt0 = rowt * 128;              // token base
    const int e0 = col * 128;
    const int batch = rowt >> 3;
    const u16* B = (MODE == 1) ? B0 + (size_t)batch * 262144 : B0;
    const int arow0 = (MODE == 2) ? e0 : tt0;
    const int brow0 = (MODE == 2) ? tt0 : e0;

    size_t gA[4], gB[4];
    u16 *ldsA[4], *ldsB[4];
#pragma unroll
    for (int i = 0; i < 4; ++i) {
        const int rr = w * 32 + i * 8 + (l >> 3);
        const int sw = ((l & 7) ^ (rr & 7)) * 8;
        gA[i] = (size_t)(arow0 + rr) * 512 + sw;
        gB[i] = (size_t)(brow0 + rr) * 512 + sw;
        ldsA[i] = As + (w * 32 + i * 8) * 64;
        ldsB[i] = Bs + (w * 32 + i * 8) * 64;
    }

    const int wr = w >> 1, wc = w & 1, kg = l >> 4, r16 = l & 15;
    int aoff[4][2], boff[4][2];
#pragma unroll
    for (int f = 0; f < 4; ++f)
#pragma unroll
        for (int h = 0; h < 2; ++h) {
            const int ra = wr * 64 + f * 16 + r16;
            aoff[f][h] = ra * 64 + (((h * 4 + kg) ^ (ra & 7)) * 8);
            const int rb = wc * 64 + f * 16 + r16;
            boff[f][h] = rb * 64 + (((h * 4 + kg) ^ (rb & 7)) * 8);
        }

    f32x4 acc[4][4];
#pragma unroll
    for (int i = 0; i < 4; ++i)
#pragma unroll
        for (int j = 0; j < 4; ++j) acc[i][j] = 0.f;

#pragma unroll 1
    for (int c0 = 0; c0 < 512; c0 += 64) {
        __syncthreads();
#pragma unroll
        for (int i = 0; i < 4; ++i) {
            g2l16(A + gA[i] + c0, ldsA[i]);
            g2l16(B + gB[i] + c0, ldsB[i]);
        }
        __syncthreads();
#pragma unroll
        for (int h = 0; h < 2; ++h) {
            bf16x8 av[4], bv[4];
#pragma unroll
            for (int f = 0; f < 4; ++f) {
                av[f] = *(const bf16x8*)&As[aoff[f][h]];
                bv[f] = *(const bf16x8*)&Bs[boff[f][h]];
            }
#pragma unroll
            for (int i = 0; i < 4; ++i)
#pragma unroll
                for (int j = 0; j < 4; ++j)
                    acc[i][j] = __builtin_amdgcn_mfma_f32_16x16x32_bf16(
                        av[i], bv[j], acc[i][j], 0, 0, 0);
        }
    }

    const int mb = wr * 64 + kg * 4;
    const int nb = wc * 64 + r16;
    if (MODE == 1) {
#pragma unroll
        for (int fm = 0; fm < 4; ++fm) {
            const int m0 = tt0 + mb + fm * 16;
            const float4 ra4 = *(const float4*)(rsA + m0);
            const float4 rq4 = *(const float4*)(rsQ + m0);
            const float ra_[4] = {ra4.x, ra4.y, ra4.z, ra4.w};
            const float rq_[4] = {rq4.x, rq4.y, rq4.z, rq4.w};
#pragma unroll
            for (int fn = 0; fn < 4; ++fn) {
                const int n = e0 + nb + fn * 16;
                const float bb = bias[n];
#pragma unroll
                for (int q = 0; q < 4; ++q) {
                    const size_t idx = (size_t)(m0 + q) * 512 + n;
                    const float val = acc[fm][fn][q] * ra_[q] + bb +
                                      bf16f(uout[idx]) * rq_[q];
                    uout[idx] = bf16_rn(val);
                }
            }
        }
    } else {
#pragma unroll
        for (int fm = 0; fm < 4; ++fm)
#pragma unroll
            for (int fn = 0; fn < 4; ++fn) {
                const int ntok = (tt0 & 1023) + nb + fn * 16;
#pragma unroll
                for (int q = 0; q < 4; ++q) {
                    const int e = e0 + mb + fm * 16 + q;
                    fout[((size_t)(batch * D_ + e) << 10) + ntok] =
                        acc[fm][fn][q] + bias[e];
                }
            }
    }
}

// ---------------- launcher ----------------

extern "C" void kernel_launch(void* const* d_in, const int* in_sizes, int n_in,
                              void* d_out, int out_size, void* d_ws, size_t ws_size,
                              hipStream_t stream) {
    const float* x  = (const float*)d_in[0];
    const float* Wq = (const float*)d_in[1];
    const float* bq = (const float*)d_in[2];
    const float* Wk = (const float*)d_in[3];
    const float* bk = (const float*)d_in[4];
    const float* wg = (const float*)d_in[5];
    const float* Wp = (const float*)d_in[6];
    const float* bp = (const float*)d_in[7];
    const float* Wf = (const float*)d_in[8];
    const float* bf = (const float*)d_in[9];
    float* out = (float*)d_out;

    // ws map (bytes), peak ~98 MB:
    // [0,32M)   Xbf (dead after mgemm0) -> [0,16M) WpG
    // [32M,64M) Qraw bf16 -> Y (mgemm1 in place)
    // [64M,96M) Kraw bf16
    // [96M,..)  Wqbf, Wkbf, Wfbf, then zeroed stats region:
    //           ssqQ[T] ssqK[T] qwr[T] G[B*D] Sb[B]
    char* Wb = (char*)d_ws;
    u16* Xbf = (u16*)Wb;
    u16* WpG = (u16*)Wb;
    u16* Qn  = (u16*)(Wb + 33554432ull);
    u16* Kn  = (u16*)(Wb + 67108864ull);
    char* S  = Wb + 100663296ull;
    u16* Wqbf = (u16*)S;
    u16* Wkbf = (u16*)(S + 524288ull);
    u16* Wfbf = (u16*)(S + 1048576ull);
    char* Z   = S + 1572864ull;
    float* SSQQ = (float*)Z;
    float* SSQK = (float*)(Z + 131072ull);
    float* QWR  = (float*)(Z + 262144ull);
    float* G    = (float*)(Z + 393216ull);
    float* Sb   = (float*)(Z + 458752ull);
    const size_t ZBYTES = 458752ull + 128ull;

    const dim3 blk(256);

    // 1. x -> Xbf (token-major bf16)
    convx_k<<<dim3(16, 8, 32), blk, 0, stream>>>(x, Xbf);
    // 2. weights -> bf16
    convw_k<<<dim3(128, 3), blk, 0, stream>>>(Wq, Wk, Wf, Wqbf, Wkbf, Wfbf);
    // 3. zero the stats region (atomic accumulators)
    hipMemsetAsync(Z, 0, ZBYTES, stream);
    // 4. fused q/k projection + row-norm stats
    mgemm0<<<dim3(1024), dim3(512), 0, stream>>>(Xbf, Wqbf, Wkbf, bq, bk, wg,
                                                 SSQQ, SSQK, QWR, Qn, Kn);
    // 5. finalize rscales, gctx coeff, Sb
    finalize_k<<<dim3(128), blk, 0, stream>>>(SSQQ, SSQK, QWR, Sb);
    // 6. graw = sum_n coeff_n * qraw_n
    gctx_k<<<dim3(8, B_), dim3(512), 0, stream>>>(QWR, Qn, G);
    // 7. WpG[b] = Wp * graw[b] * f_b
    scalewp_k<<<dim3(128, B_), blk, 0, stream>>>(Wp, G, Sb, WpG);
    // 8. Y = k_hat @ WpG[b]^T + bp + q_hat  (bf16, in place over Qn)
    mgemm12<1><<<dim3(1024), blk, 0, stream>>>(Kn, WpG, bp, SSQK, SSQQ, Qn,
                                               nullptr);
    // 9. out[b][e][n] = Wf x Y^T + bf  (fp32, final layout)
    mgemm12<2><<<dim3(1024), blk, 0, stream>>>(Wfbf, Qn, bf, nullptr, nullptr,
                                               nullptr, out);
}

// Round 10
// 149.455 us; speedup vs baseline: 6.8982x; 1.0515x over previous
//
#include <hip/hip_runtime.h>
#include <math.h>

// Problem constants
#define B_ 32
#define D_ 512
#define N_ 1024
#define T_ 32768
#define SCALE 0.04419417382415922f  // 512^-0.5

typedef unsigned short u16;
typedef __attribute__((ext_vector_type(8))) short bf16x8;
typedef __attribute__((ext_vector_type(4))) float f32x4;
typedef __attribute__((ext_vector_type(8))) unsigned short u16x8;

__device__ __forceinline__ u16 bf16_rn(float f) {
    unsigned u = __float_as_uint(f);
    u += 0x7FFFu + ((u >> 16) & 1u);
    return (u16)(u >> 16);
}
__device__ __forceinline__ float bf16f(u16 h) {
    return __uint_as_float(((unsigned)h) << 16);
}

// async global->LDS, 16B/lane; LDS dest = wave-uniform base (+lane*16 by HW)
__device__ __forceinline__ void g2l16(const u16* g, u16* lds) {
    __builtin_amdgcn_global_load_lds(
        (const __attribute__((address_space(1))) unsigned int*)g,
        (__attribute__((address_space(3))) unsigned int*)lds, 16, 0, 0);
}

__device__ __forceinline__ float waveRedSum(float v) {
#pragma unroll
    for (int off = 32; off > 0; off >>= 1) v += __shfl_xor(v, off, 64);
    return v;
}

// ---------------- conversion kernels ----------------

// Wq/Wk/Wf [512][512] fp32 -> bf16
__global__ __launch_bounds__(256) void convw_k(const float* __restrict__ W0,
                                               const float* __restrict__ W1,
                                               const float* __restrict__ W2,
                                               u16* O0, u16* O1, u16* O2) {
    const int s = blockIdx.y;
    const float* src = (s == 0) ? W0 : ((s == 1) ? W1 : W2);
    u16* O = (s == 0) ? O0 : ((s == 1) ? O1 : O2);
    const size_t i0 = (size_t)blockIdx.x * 2048 + threadIdx.x * 8;
    u16 o[8];
#pragma unroll
    for (int j = 0; j < 8; ++j) o[j] = bf16_rn(src[i0 + j]);
    *(u16x8*)&O[i0] = *(const u16x8*)&o[0];
}

// ---------------- small math kernels ----------------

// finalize per-row norms: ssqQ/ssqK -> rscale (in place), qwr -> gctx coeff
// c_n = (raw.wg)*rsQ^2 ; Sb[b] += (qw')^2 where qw' = (raw.wg)*rsQ
__global__ __launch_bounds__(256) void finalize_k(float* __restrict__ ssqQ,
                                                  float* __restrict__ ssqK,
                                                  float* __restrict__ qwr,
                                                  float* __restrict__ Sb) {
    __shared__ float red[4];
    const int i = blockIdx.x * 256 + threadIdx.x;
    const float rq = 1.f / fmaxf(sqrtf(ssqQ[i]), 1e-12f);
    ssqQ[i] = rq;
    const float rk = 1.f / fmaxf(sqrtf(ssqK[i]), 1e-12f);
    ssqK[i] = rk;
    const float qwp = qwr[i] * rq;   // normalized-q dot wg
    qwr[i] = qwp * rq;               // coefficient for gctx (extra rsQ for q-hat)
    float s = qwp * qwp;
    s = waveRedSum(s);
    if ((threadIdx.x & 63) == 0) red[threadIdx.x >> 6] = s;
    __syncthreads();
    if (threadIdx.x == 0)
        atomicAdd(Sb + (blockIdx.x >> 2), red[0] + red[1] + red[2] + red[3]);
}

// graw[b,d] = sum_n coeff[b,n] * Qraw[b,n,d]
__global__ __launch_bounds__(512) void gctx_k(const float* __restrict__ qw,
                                              const u16* __restrict__ Qn,
                                              float* __restrict__ g) {
    const int b = blockIdx.y;
    const int n0 = blockIdx.x * 128;
    const int d = threadIdx.x;
    const u16* qp = Qn + ((size_t)b * N_ + n0) * D_ + d;
    const float* wp = qw + (size_t)b * N_ + n0;
    float acc = 0.f;
    for (int n = 0; n < 128; ++n) acc += wp[n] * bf16f(qp[(size_t)n * D_]);
    atomicAdd(g + b * D_ + d, acc);
}

// WpG[b][e][c] = bf16( Wp[e][c] * graw[b][c] * f_b ),  f_b from Sb
__global__ __launch_bounds__(256) void scalewp_k(const float* __restrict__ Wp,
                                                 const float* __restrict__ g,
                                                 const float* __restrict__ Sb,
                                                 u16* __restrict__ WpG) {
    const int b = blockIdx.y;
    const float fb = SCALE / fmaxf(SCALE * sqrtf(Sb[b]), 1e-12f);
    const size_t f0 = (size_t)blockIdx.x * 2048 + threadIdx.x * 8;
    const int c = (int)(f0 & 511);
    u16 o[8];
#pragma unroll
    for (int j = 0; j < 8; ++j)
        o[j] = bf16_rn(Wp[f0 + j] * g[b * D_ + c + j] * fb);
    *(u16x8*)&WpG[(size_t)b * 262144 + f0] = *(const u16x8*)&o[0];
}

// ---------------- GEMM 0: q/k projection, fused norm-stats ----------------
// Tile 128(M)x256(N), BK=64, 8 waves (2x4), 16x16x32 bf16 MFMA, XCD-swizzled.
// A is read DIRECTLY from x fp32 [B][C][N]: 16 coalesced dword loads/thread,
// inline bf16 convert, ds_write_b128 into stride-72 padded LDS (pad spreads
// banks; no XOR on A). B (weights bf16) staged via global_load_lds + XOR.
// Stores RAW (biased) Q/K bf16 + atomicAdd per-row sumsq and raw.wg dots.
__global__ __launch_bounds__(512, 4) void mgemm0(
        const float* __restrict__ x, const u16* __restrict__ B0,
        const u16* __restrict__ B1,
        const float* __restrict__ bias0, const float* __restrict__ bias1,
        const float* __restrict__ wg,
        float* __restrict__ ssqQ, float* __restrict__ ssqK,
        float* __restrict__ qwr, u16* uout0, u16* uout1) {
    __shared__ u16 As[128 * 72];     // padded stride 72 u16 (144B, 16B-mult)
    __shared__ u16 Bs[256 * 64];
    const int tid = threadIdx.x;
    const int l = tid & 63, w = tid >> 6;
    const int gid = blockIdx.x;
    const int xcd = gid & 7;
    const int bx = (gid >> 3) & 3;           // col tile (shares A panel)
    const int by = (gid >> 5) * 8 + xcd;     // row tile -> fixed XCD
    const int t0 = by * 128;
    const bool sel = bx >= 2;                // false: Q, true: K
    const int e0 = (bx & 1) * 256;
    const u16* B = sel ? B1 : B0;
    const float* bias = sel ? bias1 : bias0;
    u16* uout = sel ? uout1 : uout0;
    float* ssq = sel ? ssqK : ssqQ;

    // ---- A staging (direct from x): thread -> token tr, c-slice csl..csl+15
    const int tr = tid & 127;
    const int csl = (tid >> 7) * 16;
    const float* xrow = x + (((size_t)((t0 >> 10) * D_ + csl)) << 10) +
                        (t0 & 1023) + tr;
    // ---- B staging (g2l16, linear LDS + XOR-swizzled source)
    size_t gB[4];
    u16* ldsB[4];
#pragma unroll
    for (int i = 0; i < 4; ++i) {
        const int rr = w * 32 + i * 8 + (l >> 3);
        gB[i] = (size_t)(e0 + rr) * 512 + (((l & 7) ^ (rr & 7)) * 8);
        ldsB[i] = Bs + (w * 32 + i * 8) * 64;
    }

    // fragment read offsets
    const int wr = w >> 2, wc = w & 3, kg = l >> 4, r16 = l & 15;
    int aoff[4][2], boff[4][2];
#pragma unroll
    for (int f = 0; f < 4; ++f)
#pragma unroll
        for (int h = 0; h < 2; ++h) {
            const int ra = wr * 64 + f * 16 + r16;
            aoff[f][h] = ra * 72 + (h * 4 + kg) * 8;          // padded, no XOR
            const int rb = wc * 64 + f * 16 + r16;
            boff[f][h] = rb * 64 + (((h * 4 + kg) ^ (rb & 7)) * 8);
        }

    f32x4 acc[4][4];
#pragma unroll
    for (int i = 0; i < 4; ++i)
#pragma unroll
        for (int j = 0; j < 4; ++j) acc[i][j] = 0.f;

    // prologue: fetch A slice for c0=0
    float ar[16];
#pragma unroll
    for (int j = 0; j < 16; ++j) ar[j] = xrow[(size_t)j << 10];

#pragma unroll 1
    for (int s = 0; s < 8; ++s) {
        const int c0 = s * 64;
        __syncthreads();             // prior tile fully consumed
        // pack + write A (data loaded last phase)
        u16 pk[16];
#pragma unroll
        for (int j = 0; j < 16; ++j) pk[j] = bf16_rn(ar[j]);
        *(u16x8*)&As[tr * 72 + csl]     = *(const u16x8*)&pk[0];
        *(u16x8*)&As[tr * 72 + csl + 8] = *(const u16x8*)&pk[8];
        // B tile via async load
#pragma unroll
        for (int i = 0; i < 4; ++i) g2l16(B + gB[i] + c0, ldsB[i]);
        // prefetch next A slice (drains together with g2l16 at the barrier)
        if (s < 7) {
#pragma unroll
            for (int j = 0; j < 16; ++j)
                ar[j] = xrow[(size_t)(c0 + 64 + j) << 10];
        }
        __syncthreads();             // vmcnt/lgkm drain -> LDS ready
#pragma unroll
        for (int h = 0; h < 2; ++h) {
            bf16x8 av[4], bv[4];
#pragma unroll
            for (int f = 0; f < 4; ++f) {
                av[f] = *(const bf16x8*)&As[aoff[f][h]];
                bv[f] = *(const bf16x8*)&Bs[boff[f][h]];
            }
#pragma unroll
            for (int i = 0; i < 4; ++i)
#pragma unroll
                for (int j = 0; j < 4; ++j)
                    acc[i][j] = __builtin_amdgcn_mfma_f32_16x16x32_bf16(
                        av[i], bv[j], acc[i][j], 0, 0, 0);
        }
    }

    // epilogue: raw store + row sumsq / wg-dot partials
    const int mb = wr * 64 + kg * 4;
    const int nb = wc * 64 + r16;
    float bb[4], wgv[4];
#pragma unroll
    for (int fn = 0; fn < 4; ++fn) {
        const int n = e0 + nb + fn * 16;
        bb[fn] = bias[n];
        wgv[fn] = sel ? 0.f : wg[n];
    }
#pragma unroll
    for (int fm = 0; fm < 4; ++fm) {
#pragma unroll
        for (int q = 0; q < 4; ++q) {
            const int m = t0 + mb + fm * 16 + q;
            float s2 = 0.f, wd = 0.f;
#pragma unroll
            for (int fn = 0; fn < 4; ++fn) {
                const float val = acc[fm][fn][q] + bb[fn];
                uout[(size_t)m * 512 + e0 + nb + fn * 16] = bf16_rn(val);
                s2 += val * val;
                wd += val * wgv[fn];
            }
#pragma unroll
            for (int off = 1; off < 16; off <<= 1) {
                s2 += __shfl_xor(s2, off, 64);
                wd += __shfl_xor(wd, off, 64);
            }
            if (r16 == 0) {
                atomicAdd(ssq + m, s2);
                if (!sel) atomicAdd(qwr + m, wd);
            }
        }
    }
}

// ---------------- GEMM 1/2: 128x128, 4 waves, XCD-swizzled ----------------
// MODE 1: A=Kraw; B=WpG[batch]; out bf16 in place over Qraw:
//         val = acc*rsK[m] + bp[n] + qraw*rsQ[m]
//         decode pins BATCH -> XCD so WpG[b] is fetched by one L2 only.
// MODE 2: A=Wf rows(e); B=Y rows(t); fp32 transposed store out[b][e][n];
//         decode pins token-tile -> XCD (B-panel reuse).
template <int MODE>
__global__ __launch_bounds__(256) void mgemm12(
        const u16* __restrict__ A, const u16* __restrict__ B0,
        const float* __restrict__ bias,
        const float* __restrict__ rsA, const float* __restrict__ rsQ,
        u16* uout, float* __restrict__ fout) {
    __shared__ u16 As[128 * 64];
    __shared__ u16 Bs[128 * 64];
    const int tid = threadIdx.x;
    const int l = tid & 63, w = tid >> 6;
    const int gid = blockIdx.x;
    const int xcd = gid & 7;

    int rowt, col, batch;
    if (MODE == 1) {
        const int j = gid >> 3;
        batch = (j >> 5) * 8 + xcd;          // batch -> fixed XCD
        const int r = j & 31;
        rowt = batch * 8 + (r >> 2);
        col = r & 3;
    } else {
        col = (gid >> 3) & 3;                // e tile
        rowt = (gid >> 5) * 8 + xcd;         // token tile -> fixed XCD
        batch = rowt >> 3;
    }
    const int tt0 = rowt * 128;              // token base
    const int e0 = col * 128;
    const u16* B = (MODE == 1) ? B0 + (size_t)batch * 262144 : B0;
    const int arow0 = (MODE == 2) ? e0 : tt0;
    const int brow0 = (MODE == 2) ? tt0 : e0;

    size_t gA[4], gB[4];
    u16 *ldsA[4], *ldsB[4];
#pragma unroll
    for (int i = 0; i < 4; ++i) {
        const int rr = w * 32 + i * 8 + (l >> 3);
        const int sw = ((l & 7) ^ (rr & 7)) * 8;
        gA[i] = (size_t)(arow0 + rr) * 512 + sw;
        gB[i] = (size_t)(brow0 + rr) * 512 + sw;
        ldsA[i] = As + (w * 32 + i * 8) * 64;
        ldsB[i] = Bs + (w * 32 + i * 8) * 64;
    }

    const int wr = w >> 1, wc = w & 1, kg = l >> 4, r16 = l & 15;
    int aoff[4][2], boff[4][2];
#pragma unroll
    for (int f = 0; f < 4; ++f)
#pragma unroll
        for (int h = 0; h < 2; ++h) {
            const int ra = wr * 64 + f * 16 + r16;
            aoff[f][h] = ra * 64 + (((h * 4 + kg) ^ (ra & 7)) * 8);
            const int rb = wc * 64 + f * 16 + r16;
            boff[f][h] = rb * 64 + (((h * 4 + kg) ^ (rb & 7)) * 8);
        }

    f32x4 acc[4][4];
#pragma unroll
    for (int i = 0; i < 4; ++i)
#pragma unroll
        for (int j = 0; j < 4; ++j) acc[i][j] = 0.f;

#pragma unroll 1
    for (int c0 = 0; c0 < 512; c0 += 64) {
        __syncthreads();
#pragma unroll
        for (int i = 0; i < 4; ++i) {
            g2l16(A + gA[i] + c0, ldsA[i]);
            g2l16(B + gB[i] + c0, ldsB[i]);
        }
        __syncthreads();
#pragma unroll
        for (int h = 0; h < 2; ++h) {
            bf16x8 av[4], bv[4];
#pragma unroll
            for (int f = 0; f < 4; ++f) {
                av[f] = *(const bf16x8*)&As[aoff[f][h]];
                bv[f] = *(const bf16x8*)&Bs[boff[f][h]];
            }
#pragma unroll
            for (int i = 0; i < 4; ++i)
#pragma unroll
                for (int j = 0; j < 4; ++j)
                    acc[i][j] = __builtin_amdgcn_mfma_f32_16x16x32_bf16(
                        av[i], bv[j], acc[i][j], 0, 0, 0);
        }
    }

    const int mb = wr * 64 + kg * 4;
    const int nb = wc * 64 + r16;
    if (MODE == 1) {
#pragma unroll
        for (int fm = 0; fm < 4; ++fm) {
            const int m0 = tt0 + mb + fm * 16;
            const float4 ra4 = *(const float4*)(rsA + m0);
            const float4 rq4 = *(const float4*)(rsQ + m0);
            const float ra_[4] = {ra4.x, ra4.y, ra4.z, ra4.w};
            const float rq_[4] = {rq4.x, rq4.y, rq4.z, rq4.w};
#pragma unroll
            for (int fn = 0; fn < 4; ++fn) {
                const int n = e0 + nb + fn * 16;
                const float bb = bias[n];
#pragma unroll
                for (int q = 0; q < 4; ++q) {
                    const size_t idx = (size_t)(m0 + q) * 512 + n;
                    const float val = acc[fm][fn][q] * ra_[q] + bb +
                                      bf16f(uout[idx]) * rq_[q];
                    uout[idx] = bf16_rn(val);
                }
            }
        }
    } else {
#pragma unroll
        for (int fm = 0; fm < 4; ++fm)
#pragma unroll
            for (int fn = 0; fn < 4; ++fn) {
                const int ntok = (tt0 & 1023) + nb + fn * 16;
#pragma unroll
                for (int q = 0; q < 4; ++q) {
                    const int e = e0 + mb + fm * 16 + q;
                    fout[((size_t)(batch * D_ + e) << 10) + ntok] =
                        acc[fm][fn][q] + bias[e];
                }
            }
    }
}

// ---------------- launcher ----------------

extern "C" void kernel_launch(void* const* d_in, const int* in_sizes, int n_in,
                              void* d_out, int out_size, void* d_ws, size_t ws_size,
                              hipStream_t stream) {
    const float* x  = (const float*)d_in[0];
    const float* Wq = (const float*)d_in[1];
    const float* bq = (const float*)d_in[2];
    const float* Wk = (const float*)d_in[3];
    const float* bk = (const float*)d_in[4];
    const float* wg = (const float*)d_in[5];
    const float* Wp = (const float*)d_in[6];
    const float* bp = (const float*)d_in[7];
    const float* Wf = (const float*)d_in[8];
    const float* bf = (const float*)d_in[9];
    float* out = (float*)d_out;

    // ws map (bytes), peak ~98 MB:
    // [0,16M)   WpG
    // [32M,64M) Qraw bf16 -> Y (mgemm1 in place)
    // [64M,96M) Kraw bf16
    // [96M,..)  Wqbf, Wkbf, Wfbf, then zeroed stats region:
    //           ssqQ[T] ssqK[T] qwr[T] G[B*D] Sb[B]
    char* Wb = (char*)d_ws;
    u16* WpG = (u16*)Wb;
    u16* Qn  = (u16*)(Wb + 33554432ull);
    u16* Kn  = (u16*)(Wb + 67108864ull);
    char* S  = Wb + 100663296ull;
    u16* Wqbf = (u16*)S;
    u16* Wkbf = (u16*)(S + 524288ull);
    u16* Wfbf = (u16*)(S + 1048576ull);
    char* Z   = S + 1572864ull;
    float* SSQQ = (float*)Z;
    float* SSQK = (float*)(Z + 131072ull);
    float* QWR  = (float*)(Z + 262144ull);
    float* G    = (float*)(Z + 393216ull);
    float* Sb   = (float*)(Z + 458752ull);
    const size_t ZBYTES = 458752ull + 128ull;

    const dim3 blk(256);

    // 1. weights -> bf16
    convw_k<<<dim3(128, 3), blk, 0, stream>>>(Wq, Wk, Wf, Wqbf, Wkbf, Wfbf);
    // 2. zero the stats region (atomic accumulators)
    hipMemsetAsync(Z, 0, ZBYTES, stream);
    // 3. fused q/k projection (direct x read) + row-norm stats
    mgemm0<<<dim3(1024), dim3(512), 0, stream>>>(x, Wqbf, Wkbf, bq, bk, wg,
                                                 SSQQ, SSQK, QWR, Qn, Kn);
    // 4. finalize rscales, gctx coeff, Sb
    finalize_k<<<dim3(128), blk, 0, stream>>>(SSQQ, SSQK, QWR, Sb);
    // 5. graw = sum_n coeff_n * qraw_n
    gctx_k<<<dim3(8, B_), dim3(512), 0, stream>>>(QWR, Qn, G);
    // 6. WpG[b] = Wp * graw[b] * f_b
    scalewp_k<<<dim3(128, B_), blk, 0, stream>>>(Wp, G, Sb, WpG);
    // 7. Y = k_hat @ WpG[b]^T + bp + q_hat  (bf16, in place over Qn)
    mgemm12<1><<<dim3(1024), blk, 0, stream>>>(Kn, WpG, bp, SSQK, SSQQ, Qn,
                                               nullptr);
    // 8. out[b][e][n] = Wf x Y^T + bf  (fp32, final layout)
    mgemm12<2><<<dim3(1024), blk, 0, stream>>>(Wfbf, Qn, bf, nullptr, nullptr,
                                               nullptr, out);
}